// Round 1
// baseline (627.050 us; speedup 1.0000x reference)
//
#include <hip/hip_runtime.h>

// Problem: 3x3 reflect-padded patch extraction.
// x: [8, 256, 256, 32] f32  ->  out: [8, 256, 256, 288] f32
// out[b,h,w, c*9 + i] = x[b, refl(h + i/3 - 1), refl(w + i%3 - 1), c]
// refl: np.pad mode='reflect' (no edge repeat): -1 -> 1, N -> N-2.

#define BB 8
#define HH 256
#define WW 256
#define CC 32
#define TAPS 9
#define OUTC (CC * TAPS)   // 288
#define TW 64              // w-tile per block
#define NTW (WW / TW)      // 4 tiles per row

__device__ __forceinline__ int refl(int i, int n) {
    // valid for i in [-1, n]
    return i < 0 ? -i : (i >= n ? 2 * n - 2 - i : i);
}

__global__ __launch_bounds__(256) void patch3x3_kernel(
    const float* __restrict__ x, float* __restrict__ out) {
    const int blk = blockIdx.x;
    const int wt = blk % NTW;
    const int h  = (blk / NTW) % HH;
    const int b  = blk / (NTW * HH);
    const int w0 = wt * TW;

    // LDS: 3 input rows x (TW+2) w-positions x 32 channels
    __shared__ float lds[3][TW + 2][CC];

    // ---- stage global -> LDS, float4 over channels (coalesced) ----
    // 3 * 66 * 8 = 1584 float4 loads
    const int nload4 = 3 * (TW + 2) * (CC / 4);
    for (int idx = threadIdx.x; idx < nload4; idx += blockDim.x) {
        const int c4 = idx % (CC / 4);
        const int wl = (idx / (CC / 4)) % (TW + 2);
        const int r  = idx / ((CC / 4) * (TW + 2));
        const int gh = refl(h + r - 1, HH);
        const int gw = refl(w0 + wl - 1, WW);
        const float4* src =
            (const float4*)(x + (((b * HH + gh) * WW + gw) * CC)) + c4;
        ((float4*)&lds[r][wl][0])[c4] = *src;
    }
    __syncthreads();

    // ---- emit output tile: TW pixels * 72 float4 each, coalesced stores ----
    float4* outp = (float4*)(out + (size_t)(((b * HH + h) * WW + w0)) * OUTC);
    const int nout4 = TW * (OUTC / 4);   // 4608
    for (int idx = threadIdx.x; idx < nout4; idx += blockDim.x) {
        const int j = idx % (OUTC / 4);  // float4 index within pixel, 0..71
        const int p = idx / (OUTC / 4);  // pixel within tile
        const int f = 4 * j;             // flat (c*9+i) of first component
        float4 v;
#pragma unroll
        for (int k = 0; k < 4; ++k) {
            const int fk = f + k;
            const int c  = fk / TAPS;    // compile-time divisor -> magic mul
            const int i  = fk % TAPS;
            const int ki = i / 3;
            const int kj = i % 3;
            // input pixel w0 + p + kj - 1 -> local index p + kj
            ((float*)&v)[k] = lds[ki][p + kj][c];
        }
        outp[idx] = v;
    }
}

extern "C" void kernel_launch(void* const* d_in, const int* in_sizes, int n_in,
                              void* d_out, int out_size, void* d_ws, size_t ws_size,
                              hipStream_t stream) {
    const float* x = (const float*)d_in[0];
    float* out = (float*)d_out;
    const int nblocks = BB * HH * NTW;   // 8192
    patch3x3_kernel<<<nblocks, 256, 0, stream>>>(x, out);
}